// Round 5
// baseline (1227.374 us; speedup 1.0000x reference)
//
#include <hip/hip_runtime.h>
#include <stdint.h>

// ---------------- problem constants ----------------
#define T_TOK   8192          // B*S
#define D_DIM   1024
#define FF_DIM  4096
#define E_NUM   8
#define SLOT_MAX 18432        // 16384 + 8*256 (worst-case 256-padded slots)
#define RT_MAX  104           // 72 moe row-tiles + 32 dense row-tiles (256-row tiles)

typedef unsigned int   u32;
typedef unsigned short u16;
typedef __attribute__((ext_vector_type(4))) float  f32x4;
typedef __attribute__((ext_vector_type(4))) float  f4;
typedef __attribute__((ext_vector_type(8))) short  bf16x8;   // 8 bf16 = 4 VGPR
typedef __attribute__((ext_vector_type(8))) unsigned short u16x8;

__device__ __forceinline__ u16 f2bf(float f) {              // RNE f32->bf16
  u32 u = __builtin_bit_cast(u32, f);
  return (u16)((u + 0x7fffu + ((u >> 16) & 1u)) >> 16);
}
__device__ __forceinline__ float bf2f(u16 h) {
  u32 u = ((u32)h) << 16; return __builtin_bit_cast(float, u);
}

typedef const __attribute__((address_space(1))) u32* gp1_t;
typedef __attribute__((address_space(3))) u32*       lp3_t;
__device__ __forceinline__ void gload16(const u16* g, u16* l) {
  // async global->LDS, 16B/lane, LDS dest = wave-uniform base + lane*16 (linear)
  __builtin_amdgcn_global_load_lds((gp1_t)(const void*)g, (lp3_t)l, 16, 0, 0);
}

// ---------------- K0: zero header ----------------
__global__ void k_init(int* hdr) { if (threadIdx.x < 64) hdr[threadIdx.x] = 0; }

// ---------------- K1: router + gate (wave per token) ----------------
__global__ __launch_bounds__(256) void k_route(
    const float* __restrict__ x, const float* __restrict__ Wr, const float* __restrict__ br,
    const float* __restrict__ Wg, const float* __restrict__ bg,
    int* __restrict__ hdr, int4* __restrict__ tok_sel, float4* __restrict__ tok_wf)
{
  int w = threadIdx.x >> 6, l = threadIdx.x & 63;
  int t = blockIdx.x * 4 + w;
  const float* xt = x + (size_t)t * D_DIM;
  float p[10];
  #pragma unroll
  for (int i = 0; i < 10; ++i) p[i] = 0.f;
  for (int j = 0; j < D_DIM / 64; ++j) {
    int d = j * 64 + l;
    float xv = xt[d];
    p[0] += xv * Wr[d * 2 + 0];
    p[1] += xv * Wr[d * 2 + 1];
    f4 g0 = *(const f4*)&Wg[d * 8];
    f4 g1 = *(const f4*)&Wg[d * 8 + 4];
    p[2] += xv * g0[0]; p[3] += xv * g0[1]; p[4] += xv * g0[2]; p[5] += xv * g0[3];
    p[6] += xv * g1[0]; p[7] += xv * g1[1]; p[8] += xv * g1[2]; p[9] += xv * g1[3];
  }
  #pragma unroll
  for (int off = 32; off; off >>= 1) {
    #pragma unroll
    for (int i = 0; i < 10; ++i) p[i] += __shfl_xor(p[i], off, 64);
  }
  if (l == 0) {
    float a0 = p[0] + br[0], a1 = p[1] + br[1];
    float m  = fmaxf(a0, a1);
    float e0 = __expf(a0 - m), e1 = __expf(a1 - m);
    float rs = 1.f / (e0 + e1);
    float rp0 = e0 * rs, rp1 = e1 * rs;
    float g[E_NUM]; float gm = -1e30f;
    #pragma unroll
    for (int e = 0; e < E_NUM; ++e) { g[e] = p[2 + e] + bg[e]; gm = fmaxf(gm, g[e]); }
    int i0 = 0;
    #pragma unroll
    for (int e = 1; e < E_NUM; ++e) if (g[e] > g[i0]) i0 = e;      // earliest max tiebreak
    int i1 = (i0 == 0) ? 1 : 0;
    #pragma unroll
    for (int e = 0; e < E_NUM; ++e) if (e != i0 && g[e] > g[i1]) i1 = e;
    float x0 = __expf(g[i0] - gm), x1 = __expf(g[i1] - gm);
    float s = 1.f / (x0 + x1);
    int r0 = atomicAdd(&hdr[i0], 1);
    int r1 = atomicAdd(&hdr[i1], 1);
    tok_sel[t] = make_int4(i0, r0, i1, r1);
    tok_wf[t]  = make_float4(x0 * s, x1 * s, rp0, rp1);
  }
}

// ---------------- K2: padded offsets + tile map + perm=-1 ----------------
__global__ __launch_bounds__(256) void k_offsets(int* __restrict__ hdr,
                                                 int4* __restrict__ tilemap,
                                                 int* __restrict__ perm)
{
  __shared__ int soff[E_NUM + 1];
  int tid = threadIdx.x;
  if (tid == 0) {
    int acc = 0;
    for (int e = 0; e < E_NUM; ++e) {
      soff[e] = acc; hdr[8 + e] = acc;
      acc += (hdr[e] + 255) & ~255;                // pad each expert to 256
    }
    soff[E_NUM] = acc;
    hdr[16] = acc;                                 // nslots_padded
    hdr[17] = acc >> 8;                            // moe row-tiles (256-row)
    hdr[18] = (acc >> 8) + T_TOK / 256;            // total row-tiles
  }
  __syncthreads();
  int nmoe = soff[E_NUM] >> 8;
  for (int rt = tid; rt < RT_MAX; rt += 256) {
    int4 ent;
    if (rt < nmoe) {
      int row0 = rt * 256;
      int e = 0;
      while (e < E_NUM - 1 && row0 >= soff[e + 1]) ++e;
      ent = make_int4(0, row0, e, 0);
    } else if (rt < nmoe + T_TOK / 256) {
      ent = make_int4(1, (rt - nmoe) * 256, -1, 0);
    } else {
      ent = make_int4(-1, 0, 0, 0);
    }
    tilemap[rt] = ent;
  }
  for (int s = tid; s < SLOT_MAX; s += 256) perm[s] = -1;
}

// ---------------- K3: scatter token -> slots ----------------
__global__ void k_scatter(const int4* __restrict__ tok_sel, const int* __restrict__ hdr,
                          int* __restrict__ perm, int2* __restrict__ tok_slot)
{
  int t = blockIdx.x * 256 + threadIdx.x;
  if (t >= T_TOK) return;
  int4 s = tok_sel[t];
  int s0 = hdr[8 + s.x] + s.y;
  int s1 = hdr[8 + s.z] + s.w;
  perm[s0] = t; perm[s1] = t;
  tok_slot[t] = make_int2(s0, s1);
}

// ---------------- K4: cast x -> bf16 ----------------
__global__ void k_cast(const float* __restrict__ x, u16* __restrict__ xb, int n8) {
  int i = blockIdx.x * 256 + threadIdx.x;
  if (i >= n8) return;
  const f4* src = (const f4*)x + (size_t)i * 2;
  f4 a = src[0], b = src[1];
  u16x8 o;
  o[0]=f2bf(a[0]); o[1]=f2bf(a[1]); o[2]=f2bf(a[2]); o[3]=f2bf(a[3]);
  o[4]=f2bf(b[0]); o[5]=f2bf(b[1]); o[6]=f2bf(b[2]); o[7]=f2bf(b[3]);
  ((u16x8*)xb)[i] = o;
}

// ---------------- K5: gather x rows into slot order ----------------
__global__ __launch_bounds__(256) void k_gather(const u16* __restrict__ xb,
                                                const int* __restrict__ perm,
                                                const int* __restrict__ hdr,
                                                u16* __restrict__ xg)
{
  int nslots = hdr[16];
  int row = blockIdx.x * 2 + (threadIdx.x >> 7);
  if (row >= nslots) return;
  int lane = threadIdx.x & 127;
  int t = perm[row];
  u16x8* dst = (u16x8*)(xg + (size_t)row * D_DIM) + lane;
  if (t < 0) { u16x8 z = {0,0,0,0,0,0,0,0}; *dst = z; }
  else       { *dst = *((const u16x8*)(xb + (size_t)t * D_DIM) + lane); }
}

// ---------------- K6: cast+transpose f32 [R,C] -> bf16 [C,R] ----------------
__global__ __launch_bounds__(256) void k_tcast(const float* __restrict__ src,
                                               u16* __restrict__ dst, int R, int C)
{
  const float* s = src + (size_t)blockIdx.z * R * C;
  u16* d = dst + (size_t)blockIdx.z * R * C;
  __shared__ float tile[64][65];
  int tr = blockIdx.y, tc = blockIdx.x;
  int t = threadIdx.x;
  #pragma unroll
  for (int p = 0; p < 4; ++p) {
    int r = p * 16 + (t >> 4);
    int c4 = (t & 15) * 4;
    f4 v = *(const f4*)&s[(size_t)(tr * 64 + r) * C + tc * 64 + c4];
    tile[r][c4+0] = v[0]; tile[r][c4+1] = v[1]; tile[r][c4+2] = v[2]; tile[r][c4+3] = v[3];
  }
  __syncthreads();
  #pragma unroll
  for (int q = 0; q < 2; ++q) {
    int oc = q * 32 + (t >> 3);
    int r8 = (t & 7) * 8;
    u16x8 o;
    #pragma unroll
    for (int j = 0; j < 8; ++j) o[j] = f2bf(tile[r8 + j][oc]);
    *(u16x8*)&d[(size_t)(tc * 64 + oc) * R + tr * 64 + r8] = o;
  }
}

// ------- K7/K8: grouped GEMM, 256x256, pipelined 4-phase (read-ahead) -------
// 8 waves (2M x 4N), per-wave 128x64 out. LDS 128KB: A = 2dbuf x 2half x 128x64,
// B same (byte: A region (b*2+h)*16384, B +65536). Frag reads XOR-swizzled
// (byte ^= (row&7)<<4) via pre-swizzled STAGE SOURCE (rule #21).
// Per K-tile, 4 phases, ONE barrier each; each phase issues ds_reads for the
// NEXT quadrant so read issue/latency hides under the current MFMA cluster:
//   F0: read b1(t);  stage A-h1(t+1)@b^1;          MFMA Q0(a0,b0); lgkm0; BAR
//   F1: read a1(t);  stage B-h0(t+2)@b;            MFMA Q1(a0,b1); lgkm0; BAR
//   F2:              stage B-h1(t+2)+A-h0(t+2)@b;  MFMA Q2(a1,b1);        BAR
//   F3: vmcnt(6); read a0'(t+1)@b^1 (a0 dead since Q1 -> no WAR);
//       MFMA Q3(a1,b0); read b0'(t+1)@b^1 (after Q3: b0 WAR);              BAR
// Ledger: lgkm0 at F0/F1 ends because those reads' regions are staged exactly
// one phase later; F3's reads drain at next-tile first use, >=1 barrier before
// their regions are re-staged. vmcnt(6): queue holds 7 half-stages (14 loads);
// retiring the 4 oldest (8 loads) == tile t+1 fully landed. Never 0 in-loop.
#define LGKM0() { asm volatile("s_waitcnt lgkmcnt(0)" ::: "memory"); \
                  __builtin_amdgcn_sched_barrier(0); }
#define BAR()   __builtin_amdgcn_s_barrier()

template <int RELU>
__global__ __launch_bounds__(512, 2) void k_gemm8p(
    const u16* __restrict__ Amoe, const u16* __restrict__ Aden,
    const u16* __restrict__ Bexp, const u16* __restrict__ Bden,
    const float* __restrict__ biasexp, const float* __restrict__ biasden,
    u16* __restrict__ Omoe, u16* __restrict__ Oden,
    const int* __restrict__ hdr, const int4* __restrict__ tilemap,
    int K, int N, long bexp_stride, int biasexp_stride, int lg2gx)
{
  // bijective XCD-aware swizzle (nwg % 8 == 0 for both launches)
  int gx  = 1 << lg2gx;
  int nwg = gx * gridDim.y;
  int lin = blockIdx.y * gx + blockIdx.x;
  int sw  = (lin & 7) * (nwg >> 3) + (lin >> 3);
  int ct  = sw & (gx - 1);
  int rt  = sw >> lg2gx;
  if (rt >= hdr[18]) return;

  int4 ent = tilemap[rt];
  const u16* A; const u16* B; const float* bias; u16* O;
  if (ent.x == 1) { A = Aden; B = Bden; bias = biasden; O = Oden; }
  else {
    A = Amoe; B = Bexp + (size_t)ent.z * bexp_stride;
    bias = biasexp + (size_t)ent.z * biasexp_stride;
    O = Omoe;
  }
  const int row0 = ent.y;

  __shared__ __align__(16) u16 lds[65536];     // 128KB

  const int tid = threadIdx.x;
  const int wid = tid >> 6, l = tid & 63;
  const int wm = wid >> 2, wn = wid & 3;

  // --- staging source (pre-swizzled k within each row; LDS dest linear) ---
  const int skel = ((l & 7) ^ (l >> 3)) * 8;            // swizzled k-elem in [0,64)
  const u16* aStage = A + (size_t)(row0     + wid * 8 + (l >> 3)) * K + skel;
  const u16* bStage = B + (size_t)(ct * 256 + wid * 8 + (l >> 3)) * K + skel;

  // --- frag-read constants ---
  const int fr = l & 15, fq = l >> 4;
  const int fx = (l & 7) << 4;                           // row&7 == l&7 for frag rows
  const int cs0 = (fq * 16) ^ fx;                        // k-slice 0 byte col
  const int cs1 = (64 + fq * 16) ^ fx;                   // k-slice 1 byte col
  const char* ldsc = (const char*)lds;
  const int brow = (wn & 1) * 64;

  auto STAGE_A = [&](int tt, int h, int bb) {
    const u16* src = aStage + (size_t)(h * 128) * K + (size_t)tt * 64;
    u16* dst = &lds[(bb * 2 + h) * 8192 + wid * 512];
    gload16(src, dst);
    gload16(src + (size_t)64 * K, dst + 4096);
  };
  auto STAGE_B = [&](int tt, int h, int bb) {
    const u16* src = bStage + (size_t)(h * 128) * K + (size_t)tt * 64;
    u16* dst = &lds[32768 + (bb * 2 + h) * 8192 + wid * 512];
    gload16(src, dst);
    gload16(src + (size_t)64 * K, dst + 4096);
  };

  f32x4 acc[8][4];
  #pragma unroll
  for (int m = 0; m < 8; ++m)
    #pragma unroll
    for (int n = 0; n < 4; ++n) acc[m][n] = (f32x4){0.f, 0.f, 0.f, 0.f};

  bf16x8 a0[4][2], a1[4][2], b0[2][2], b1[2][2];

  #define READ_A0(bb) { const char* Ar = ldsc + (size_t)((bb) * 2 + wm) * 16384; \
    _Pragma("unroll") for (int j = 0; j < 4; ++j) { \
      a0[j][0] = *(const bf16x8*)(Ar + (j * 16 + fr) * 128 + cs0); \
      a0[j][1] = *(const bf16x8*)(Ar + (j * 16 + fr) * 128 + cs1); } }
  #define READ_A1(bb) { const char* Ar = ldsc + (size_t)((bb) * 2 + wm) * 16384; \
    _Pragma("unroll") for (int j = 0; j < 4; ++j) { \
      a1[j][0] = *(const bf16x8*)(Ar + (64 + j * 16 + fr) * 128 + cs0); \
      a1[j][1] = *(const bf16x8*)(Ar + (64 + j * 16 + fr) * 128 + cs1); } }
  #define READ_B0(bb) { const char* Br = ldsc + 65536 + (size_t)((bb) * 2 + (wn >> 1)) * 16384; \
    _Pragma("unroll") for (int i = 0; i < 2; ++i) { \
      b0[i][0] = *(const bf16x8*)(Br + (brow + i * 16 + fr) * 128 + cs0); \
      b0[i][1] = *(const bf16x8*)(Br + (brow + i * 16 + fr) * 128 + cs1); } }
  #define READ_B1(bb) { const char* Br = ldsc + 65536 + (size_t)((bb) * 2 + (wn >> 1)) * 16384; \
    _Pragma("unroll") for (int i = 0; i < 2; ++i) { \
      b1[i][0] = *(const bf16x8*)(Br + (brow + 32 + i * 16 + fr) * 128 + cs0); \
      b1[i][1] = *(const bf16x8*)(Br + (brow + 32 + i * 16 + fr) * 128 + cs1); } }
  #define MFMA_Q(am, bm, mo, no) { __builtin_amdgcn_s_setprio(1); \
    _Pragma("unroll") for (int j = 0; j < 4; ++j) \
      _Pragma("unroll") for (int i = 0; i < 2; ++i) { \
        acc[(mo) + j][(no) + i] = __builtin_amdgcn_mfma_f32_16x16x32_bf16(am[j][0], bm[i][0], acc[(mo) + j][(no) + i], 0, 0, 0); \
        acc[(mo) + j][(no) + i] = __builtin_amdgcn_mfma_f32_16x16x32_bf16(am[j][1], bm[i][1], acc[(mo) + j][(no) + i], 0, 0, 0); } \
    __builtin_amdgcn_s_setprio(0); }

  const int NK = K >> 6;                                 // 16 or 64

  // prologue: 7 half-tiles; vmcnt(6) retires exactly tile 0's 4 halves
  STAGE_B(0, 0, 0); STAGE_B(0, 1, 0); STAGE_A(0, 0, 0); STAGE_A(0, 1, 0);
  STAGE_B(1, 0, 1); STAGE_B(1, 1, 1); STAGE_A(1, 0, 1);
  asm volatile("s_waitcnt vmcnt(6)" ::: "memory");
  BAR();
  READ_A0(0); READ_B0(0);                                // pre-read Q0 frags

  for (int t = 0; t < NK; ++t) {
    const int b = t & 1;
    // ---- F0: read b1 (next quadrant); stage A-h1(t+1); MFMA Q0(a0,b0)
    READ_B1(b);
    if (t + 1 < NK) STAGE_A(t + 1, 1, b ^ 1);
    MFMA_Q(a0, b0, 0, 0);
    LGKM0();                       // b1 regions staged next phase
    BAR();
    // ---- F1: read a1; stage B-h0(t+2); MFMA Q1(a0,b1)
    READ_A1(b);
    if (t + 2 < NK) STAGE_B(t + 2, 0, b);
    MFMA_Q(a0, b1, 0, 2);
    LGKM0();                       // a1 regions staged next phase
    BAR();
    // ---- F2: stage B-h1(t+2)+A-h0(t+2); MFMA Q2(a1,b1)
    if (t + 2 < NK) { STAGE_B(t + 2, 1, b); STAGE_A(t + 2, 0, b); }
    MFMA_Q(a1, b1, 4, 2);
    BAR();
    // ---- F3: vmcnt; read a0'(t+1); MFMA Q3(a1,b0); read b0'(t+1)
    if (t + 1 < NK) {
      if (t + 2 < NK) { asm volatile("s_waitcnt vmcnt(6)" ::: "memory"); }
      else            { asm volatile("s_waitcnt vmcnt(0)" ::: "memory"); }
      READ_A0(b ^ 1);              // a0 dead since Q1 -> no WAR
      MFMA_Q(a1, b0, 4, 0);
      READ_B0(b ^ 1);              // b0 consumed by Q3 -> read after
    } else {
      MFMA_Q(a1, b0, 4, 0);
    }
    BAR();
  }

  // ---- epilogue: per-wave padded LDS-bounce transpose -> u16x8 stores ----
  __syncthreads();
  float bv[4];
  #pragma unroll
  for (int ni = 0; ni < 4; ++ni) bv[ni] = bias[ct * 256 + wn * 64 + ni * 16 + fr];
  float* ep = (float*)((char*)lds + wid * 4608);         // 16 x 68 floats, padded
  const int row16 = l >> 2, cg = l & 3;
  #pragma unroll
  for (int mi = 0; mi < 8; ++mi) {
    #pragma unroll
    for (int ni = 0; ni < 4; ++ni) {
      f32x4 v = acc[mi][ni];
      #pragma unroll
      for (int j = 0; j < 4; ++j) {
        float f = v[j] + bv[ni];
        if (RELU) f = fmaxf(f, 0.f);
        ep[(fq * 4 + j) * 68 + ni * 16 + fr] = f;        // stride 68: 2-way max
      }
    }
    #pragma unroll
    for (int p = 0; p < 2; ++p) {
      f4 r0 = *(f4*)&ep[row16 * 68 + (cg + p * 4) * 8];
      f4 r1 = *(f4*)&ep[row16 * 68 + (cg + p * 4) * 8 + 4];
      u16x8 o;
      o[0]=f2bf(r0[0]); o[1]=f2bf(r0[1]); o[2]=f2bf(r0[2]); o[3]=f2bf(r0[3]);
      o[4]=f2bf(r1[0]); o[5]=f2bf(r1[1]); o[6]=f2bf(r1[2]); o[7]=f2bf(r1[3]);
      int rr = row0 + wm * 128 + mi * 16 + row16;
      int cc = ct * 256 + wn * 64 + (cg + p * 4) * 8;
      *(u16x8*)&O[(size_t)rr * N + cc] = o;
    }
  }
  #undef READ_A0
  #undef READ_A1
  #undef READ_B0
  #undef READ_B1
  #undef MFMA_Q
}

// ---------------- K9: combine ----------------
__global__ __launch_bounds__(128) void k_combine(
    const u16* __restrict__ eo, const u16* __restrict__ dense_o,
    const float4* __restrict__ tok_wf, const int2* __restrict__ tok_slot,
    float* __restrict__ out)
{
  int t = blockIdx.x;
  int c8 = threadIdx.x;
  float4 wf = tok_wf[t];
  int2 sl = tok_slot[t];
  u16x8 a  = *((const u16x8*)(eo + (size_t)sl.x * D_DIM) + c8);
  u16x8 b  = *((const u16x8*)(eo + (size_t)sl.y * D_DIM) + c8);
  u16x8 dn = *((const u16x8*)(dense_o + (size_t)t * D_DIM) + c8);
  float* op = out + (size_t)t * D_DIM + c8 * 8;
  #pragma unroll
  for (int j = 0; j < 8; ++j) {
    float mo = wf.x * bf2f(a[j]) + wf.y * bf2f(b[j]);
    op[j] = wf.z * mo + wf.w * bf2f(dn[j]);
  }
}

// ---------------- launch ----------------
extern "C" void kernel_launch(void* const* d_in, const int* in_sizes, int n_in,
                              void* d_out, int out_size, void* d_ws, size_t ws_size,
                              hipStream_t stream)
{
  const float* x   = (const float*)d_in[0];
  const float* Wr  = (const float*)d_in[1];
  const float* br  = (const float*)d_in[2];
  const float* Wg  = (const float*)d_in[3];
  const float* bg  = (const float*)d_in[4];
  const float* W1  = (const float*)d_in[5];
  const float* b1  = (const float*)d_in[6];
  const float* W2  = (const float*)d_in[7];
  const float* b2  = (const float*)d_in[8];
  const float* D1  = (const float*)d_in[9];
  const float* d1b = (const float*)d_in[10];
  const float* D2  = (const float*)d_in[11];
  const float* d2b = (const float*)d_in[12];
  float* out = (float*)d_out;

  char* base = (char*)d_ws;
  size_t cur = 0;
  auto alloc = [&](size_t b) -> void* {
    void* p = base + cur; cur = (cur + b + 255) & ~(size_t)255; return p;
  };
  int*    hdr      = (int*)   alloc(256 * sizeof(int));
  int4*   tilemap  = (int4*)  alloc((size_t)RT_MAX * sizeof(int4));
  int4*   tok_sel  = (int4*)  alloc((size_t)T_TOK * sizeof(int4));
  float4* tok_wf   = (float4*)alloc((size_t)T_TOK * sizeof(float4));
  int2*   tok_slot = (int2*)  alloc((size_t)T_TOK * sizeof(int2));
  int*    perm     = (int*)   alloc((size_t)SLOT_MAX * sizeof(int));
  u16*    xb       = (u16*)   alloc((size_t)T_TOK * D_DIM * 2);
  u16*    xg       = (u16*)   alloc((size_t)SLOT_MAX * D_DIM * 2);
  u16*    W1bt     = (u16*)   alloc((size_t)E_NUM * D_DIM * FF_DIM * 2);
  u16*    W2bt     = (u16*)   alloc((size_t)E_NUM * D_DIM * FF_DIM * 2);
  u16*    D1bt     = (u16*)   alloc((size_t)D_DIM * FF_DIM * 2);
  u16*    D2bt     = (u16*)   alloc((size_t)D_DIM * FF_DIM * 2);
  u16*    h_moe    = (u16*)   alloc((size_t)SLOT_MAX * FF_DIM * 2);
  u16*    h_dense  = (u16*)   alloc((size_t)T_TOK * FF_DIM * 2);
  u16*    eo       = (u16*)   alloc((size_t)SLOT_MAX * D_DIM * 2);
  u16*    dense_o  = (u16*)   alloc((size_t)T_TOK * D_DIM * 2);
  (void)in_sizes; (void)n_in; (void)out_size; (void)ws_size; // needs ~475 MB of ws

  k_init   <<<1, 64, 0, stream>>>(hdr);
  k_route  <<<T_TOK / 4, 256, 0, stream>>>(x, Wr, br, Wg, bg, hdr, tok_sel, tok_wf);
  k_offsets<<<1, 256, 0, stream>>>(hdr, tilemap, perm);
  k_scatter<<<T_TOK / 256, 256, 0, stream>>>(tok_sel, hdr, perm, tok_slot);
  k_cast   <<<(T_TOK * D_DIM / 8) / 256, 256, 0, stream>>>(x, xb, T_TOK * D_DIM / 8);
  k_gather <<<SLOT_MAX / 2, 256, 0, stream>>>(xb, perm, hdr, xg);
  k_tcast  <<<dim3(FF_DIM / 64, D_DIM / 64, E_NUM), 256, 0, stream>>>(W1, W1bt, D_DIM, FF_DIM);
  k_tcast  <<<dim3(D_DIM / 64, FF_DIM / 64, E_NUM), 256, 0, stream>>>(W2, W2bt, FF_DIM, D_DIM);
  k_tcast  <<<dim3(FF_DIM / 64, D_DIM / 64, 1), 256, 0, stream>>>(D1, D1bt, D_DIM, FF_DIM);
  k_tcast  <<<dim3(D_DIM / 64, FF_DIM / 64, 1), 256, 0, stream>>>(D2, D2bt, FF_DIM, D_DIM);

  // GEMM1: [slots|tokens] x W1 -> relu -> h   (grid 16x104, K=1024, NK=16)
  k_gemm8p<1><<<dim3(FF_DIM / 256, RT_MAX), 512, 0, stream>>>(
      xg, xb, W1bt, D1bt, b1, d1b, h_moe, h_dense, hdr, tilemap,
      D_DIM, FF_DIM, (long)D_DIM * FF_DIM, FF_DIM, 4);
  // GEMM2: h x W2 -> eo   (grid 4x104, K=4096, NK=64)
  k_gemm8p<0><<<dim3(D_DIM / 256, RT_MAX), 512, 0, stream>>>(
      h_moe, h_dense, W2bt, D2bt, b2, d2b, eo, dense_o, hdr, tilemap,
      FF_DIM, D_DIM, (long)D_DIM * FF_DIM, D_DIM, 2);

  k_combine<<<T_TOK, 128, 0, stream>>>(eo, dense_o, tok_wf, tok_slot, out);
}

// Round 6
// 775.312 us; speedup vs baseline: 1.5831x; 1.5831x over previous
//
#include <hip/hip_runtime.h>
#include <stdint.h>

// ---------------- problem constants ----------------
#define T_TOK   8192          // B*S
#define D_DIM   1024
#define FF_DIM  4096
#define E_NUM   8
#define SLOT_MAX 18432        // 16384 + 8*256 (worst-case 256-padded slots)
#define RT_MAX  104           // 72 moe row-tiles + 32 dense row-tiles (256-row tiles)

typedef unsigned int   u32;
typedef unsigned short u16;
typedef __attribute__((ext_vector_type(4))) float  f32x4;
typedef __attribute__((ext_vector_type(4))) float  f4;
typedef __attribute__((ext_vector_type(8))) short  bf16x8;   // 8 bf16 = 4 VGPR
typedef __attribute__((ext_vector_type(8))) unsigned short u16x8;

__device__ __forceinline__ u16 f2bf(float f) {              // RNE f32->bf16
  u32 u = __builtin_bit_cast(u32, f);
  return (u16)((u + 0x7fffu + ((u >> 16) & 1u)) >> 16);
}
__device__ __forceinline__ float bf2f(u16 h) {
  u32 u = ((u32)h) << 16; return __builtin_bit_cast(float, u);
}

typedef const __attribute__((address_space(1))) u32* gp1_t;
typedef __attribute__((address_space(3))) u32*       lp3_t;
__device__ __forceinline__ void gload16(const u16* g, u16* l) {
  // async global->LDS, 16B/lane, LDS dest = wave-uniform base + lane*16 (linear)
  __builtin_amdgcn_global_load_lds((gp1_t)(const void*)g, (lp3_t)l, 16, 0, 0);
}

// ---------------- K0: zero header ----------------
__global__ void k_init(int* hdr) { if (threadIdx.x < 64) hdr[threadIdx.x] = 0; }

// ---------- K1: router + gate (wave per token) + fused x->bf16 cast ----------
__global__ __launch_bounds__(256) void k_route(
    const float* __restrict__ x, const float* __restrict__ Wr, const float* __restrict__ br,
    const float* __restrict__ Wg, const float* __restrict__ bg,
    int* __restrict__ hdr, int4* __restrict__ tok_sel, float4* __restrict__ tok_wf,
    u16* __restrict__ xb)
{
  int w = threadIdx.x >> 6, l = threadIdx.x & 63;
  int t = blockIdx.x * 4 + w;
  const float* xt = x + (size_t)t * D_DIM;
  u16* xbt = xb + (size_t)t * D_DIM;
  float p[10];
  #pragma unroll
  for (int i = 0; i < 10; ++i) p[i] = 0.f;
  for (int j = 0; j < D_DIM / 64; ++j) {
    int d = j * 64 + l;
    float xv = xt[d];
    xbt[d] = f2bf(xv);                       // fused cast (saves k_cast's re-read)
    p[0] += xv * Wr[d * 2 + 0];
    p[1] += xv * Wr[d * 2 + 1];
    f4 g0 = *(const f4*)&Wg[d * 8];
    f4 g1 = *(const f4*)&Wg[d * 8 + 4];
    p[2] += xv * g0[0]; p[3] += xv * g0[1]; p[4] += xv * g0[2]; p[5] += xv * g0[3];
    p[6] += xv * g1[0]; p[7] += xv * g1[1]; p[8] += xv * g1[2]; p[9] += xv * g1[3];
  }
  #pragma unroll
  for (int off = 32; off; off >>= 1) {
    #pragma unroll
    for (int i = 0; i < 10; ++i) p[i] += __shfl_xor(p[i], off, 64);
  }
  if (l == 0) {
    float a0 = p[0] + br[0], a1 = p[1] + br[1];
    float m  = fmaxf(a0, a1);
    float e0 = __expf(a0 - m), e1 = __expf(a1 - m);
    float rs = 1.f / (e0 + e1);
    float rp0 = e0 * rs, rp1 = e1 * rs;
    float g[E_NUM]; float gm = -1e30f;
    #pragma unroll
    for (int e = 0; e < E_NUM; ++e) { g[e] = p[2 + e] + bg[e]; gm = fmaxf(gm, g[e]); }
    int i0 = 0;
    #pragma unroll
    for (int e = 1; e < E_NUM; ++e) if (g[e] > g[i0]) i0 = e;      // earliest max tiebreak
    int i1 = (i0 == 0) ? 1 : 0;
    #pragma unroll
    for (int e = 0; e < E_NUM; ++e) if (e != i0 && g[e] > g[i1]) i1 = e;
    float x0 = __expf(g[i0] - gm), x1 = __expf(g[i1] - gm);
    float s = 1.f / (x0 + x1);
    int r0 = atomicAdd(&hdr[i0], 1);
    int r1 = atomicAdd(&hdr[i1], 1);
    tok_sel[t] = make_int4(i0, r0, i1, r1);
    tok_wf[t]  = make_float4(x0 * s, x1 * s, rp0, rp1);
  }
}

// ---------------- K2: padded offsets + tile map + perm=-1 ----------------
__global__ __launch_bounds__(256) void k_offsets(int* __restrict__ hdr,
                                                 int4* __restrict__ tilemap,
                                                 int* __restrict__ perm)
{
  __shared__ int soff[E_NUM + 1];
  int tid = threadIdx.x;
  if (tid == 0) {
    int acc = 0;
    for (int e = 0; e < E_NUM; ++e) {
      soff[e] = acc; hdr[8 + e] = acc;
      acc += (hdr[e] + 255) & ~255;                // pad each expert to 256
    }
    soff[E_NUM] = acc;
    hdr[16] = acc;                                 // nslots_padded
    hdr[17] = acc >> 8;                            // moe row-tiles (256-row)
    hdr[18] = (acc >> 8) + T_TOK / 256;            // total row-tiles
  }
  __syncthreads();
  int nmoe = soff[E_NUM] >> 8;
  for (int rt = tid; rt < RT_MAX; rt += 256) {
    int4 ent;
    if (rt < nmoe) {
      int row0 = rt * 256;
      int e = 0;
      while (e < E_NUM - 1 && row0 >= soff[e + 1]) ++e;
      ent = make_int4(0, row0, e, 0);
    } else if (rt < nmoe + T_TOK / 256) {
      ent = make_int4(1, (rt - nmoe) * 256, -1, 0);
    } else {
      ent = make_int4(-1, 0, 0, 0);
    }
    tilemap[rt] = ent;
  }
  for (int s = tid; s < SLOT_MAX; s += 256) perm[s] = -1;
}

// ---------------- K3: scatter token -> slots ----------------
__global__ void k_scatter(const int4* __restrict__ tok_sel, const int* __restrict__ hdr,
                          int* __restrict__ perm, int2* __restrict__ tok_slot)
{
  int t = blockIdx.x * 256 + threadIdx.x;
  if (t >= T_TOK) return;
  int4 s = tok_sel[t];
  int s0 = hdr[8 + s.x] + s.y;
  int s1 = hdr[8 + s.z] + s.w;
  perm[s0] = t; perm[s1] = t;
  tok_slot[t] = make_int2(s0, s1);
}

// ---------------- K5: gather x rows into slot order ----------------
__global__ __launch_bounds__(256) void k_gather(const u16* __restrict__ xb,
                                                const int* __restrict__ perm,
                                                const int* __restrict__ hdr,
                                                u16* __restrict__ xg)
{
  int nslots = hdr[16];
  int row = blockIdx.x * 2 + (threadIdx.x >> 7);
  if (row >= nslots) return;
  int lane = threadIdx.x & 127;
  int t = perm[row];
  u16x8* dst = (u16x8*)(xg + (size_t)row * D_DIM) + lane;
  if (t < 0) { u16x8 z = {0,0,0,0,0,0,0,0}; *dst = z; }
  else       { *dst = *((const u16x8*)(xb + (size_t)t * D_DIM) + lane); }
}

// ------ K6: fused cast+transpose f32 [R,C] -> bf16 [C,R], all 18 panels ------
__global__ __launch_bounds__(256) void k_tcast_all(
    const float* __restrict__ W1, const float* __restrict__ W2,
    const float* __restrict__ D1, const float* __restrict__ D2,
    u16* __restrict__ W1bt, u16* __restrict__ W2bt,
    u16* __restrict__ D1bt, u16* __restrict__ D2bt)
{
  int bid = blockIdx.x;
  int panel = bid >> 10, pb = bid & 1023;
  const float* s; u16* d; int R, C, ltc;
  if (panel < 8)       { s = W1 + (size_t)panel * D_DIM * FF_DIM; d = W1bt + (size_t)panel * D_DIM * FF_DIM; R = D_DIM;  C = FF_DIM; ltc = 6; }
  else if (panel < 16) { int e = panel - 8;
                         s = W2 + (size_t)e * FF_DIM * D_DIM;     d = W2bt + (size_t)e * FF_DIM * D_DIM;     R = FF_DIM; C = D_DIM;  ltc = 4; }
  else if (panel == 16){ s = D1; d = D1bt; R = D_DIM;  C = FF_DIM; ltc = 6; }
  else                 { s = D2; d = D2bt; R = FF_DIM; C = D_DIM;  ltc = 4; }
  int tc = pb & ((1 << ltc) - 1), tr = pb >> ltc;

  __shared__ float tile[64][65];
  int t = threadIdx.x;
  #pragma unroll
  for (int p = 0; p < 4; ++p) {
    int r = p * 16 + (t >> 4);
    int c4 = (t & 15) * 4;
    f4 v = *(const f4*)&s[(size_t)(tr * 64 + r) * C + tc * 64 + c4];
    tile[r][c4+0] = v[0]; tile[r][c4+1] = v[1]; tile[r][c4+2] = v[2]; tile[r][c4+3] = v[3];
  }
  __syncthreads();
  #pragma unroll
  for (int q = 0; q < 2; ++q) {
    int oc = q * 32 + (t >> 3);
    int r8 = (t & 7) * 8;
    u16x8 o;
    #pragma unroll
    for (int j = 0; j < 8; ++j) o[j] = f2bf(tile[r8 + j][oc]);
    *(u16x8*)&d[(size_t)(tc * 64 + oc) * R + tr * 64 + r8] = o;
  }
}

// ---- K7/K8: grouped GEMM, m201-style 4-phase/tile, BM=BN=256, BK=64 ----
// r4 skeleton (verified 266us): per phase {reads for THIS quadrant; stage;
// BAR; lgkm0; setprio+16 MFMA+setprio; BAR}. vmcnt(6) once per tile at P4.
// New in r6: all frag ds_reads are base+compile-time-immediate (4 per-lane
// base pointers, K-loop 2x-unrolled so buf index is a literal) -> no VALU
// address math in the loop. Epilogue LDS-bounce padded to stride 68 floats.
#define LGKM0() { asm volatile("s_waitcnt lgkmcnt(0)" ::: "memory"); \
                  __builtin_amdgcn_sched_barrier(0); }
#define BAR()   __builtin_amdgcn_s_barrier()

template <int RELU>
__global__ __launch_bounds__(512, 2) void k_gemm8p(
    const u16* __restrict__ Amoe, const u16* __restrict__ Aden,
    const u16* __restrict__ Bexp, const u16* __restrict__ Bden,
    const float* __restrict__ biasexp, const float* __restrict__ biasden,
    u16* __restrict__ Omoe, u16* __restrict__ Oden,
    const int* __restrict__ hdr, const int4* __restrict__ tilemap,
    int K, int N, long bexp_stride, int biasexp_stride, int lg2gx)
{
  // bijective XCD-aware swizzle (nwg % 8 == 0 for both launches)
  int gx  = 1 << lg2gx;
  int nwg = gx * gridDim.y;
  int lin = blockIdx.y * gx + blockIdx.x;
  int sw  = (lin & 7) * (nwg >> 3) + (lin >> 3);
  int ct  = sw & (gx - 1);
  int rt  = sw >> lg2gx;
  if (rt >= hdr[18]) return;

  int4 ent = tilemap[rt];
  const u16* A; const u16* B; const float* bias; u16* O;
  if (ent.x == 1) { A = Aden; B = Bden; bias = biasden; O = Oden; }
  else {
    A = Amoe; B = Bexp + (size_t)ent.z * bexp_stride;
    bias = biasexp + (size_t)ent.z * biasexp_stride;
    O = Omoe;
  }
  const int row0 = ent.y;

  __shared__ __align__(16) u16 lds[65536];     // 128KB

  const int tid = threadIdx.x;
  const int wid = tid >> 6, l = tid & 63;
  const int wm = wid >> 2, wn = wid & 3;

  // --- staging source (pre-swizzled k within each row; LDS dest linear) ---
  const int skel = ((l & 7) ^ (l >> 3)) * 8;            // swizzled k-elem in [0,64)
  const u16* aStage = A + (size_t)(row0     + wid * 8 + (l >> 3)) * K + skel;
  const u16* bStage = B + (size_t)(ct * 256 + wid * 8 + (l >> 3)) * K + skel;

  // --- frag-read base pointers; all reads = base + compile-time immediate ---
  // A byte addr = wm*16384 + row*128 + (k16*16 ^ fx) + b*32768 + h*8192 + j*2048
  // B byte addr = 65536 + (wn>>1)*16384 + (brow+row)*128 + (...) + b*32768 + nh*4096 + i*2048
  const int fr = l & 15, fq = l >> 4;
  const int fx = (l & 7) << 4;                           // row&7 == l&7 for frag rows
  const int cs0 = (fq * 16) ^ fx;
  const int cs1 = (64 + fq * 16) ^ fx;                   // == cs0 ^ 64
  const int brow = (wn & 1) * 64;
  const char* ldsc = (const char*)lds;
  const char* aP0 = ldsc + wm * 16384 + fr * 128 + cs0;
  const char* aP1 = ldsc + wm * 16384 + fr * 128 + cs1;
  const char* bP0 = ldsc + 65536 + (wn >> 1) * 16384 + (brow + fr) * 128 + cs0;
  const char* bP1 = ldsc + 65536 + (wn >> 1) * 16384 + (brow + fr) * 128 + cs1;

  auto STAGE_A = [&](int tt, int h, int bb) {
    const u16* src = aStage + (size_t)(h * 128) * K + (size_t)tt * 64;
    u16* dst = &lds[(bb * 2 + h) * 8192 + wid * 512];
    gload16(src, dst);
    gload16(src + (size_t)64 * K, dst + 4096);
  };
  auto STAGE_B = [&](int tt, int h, int bb) {
    const u16* src = bStage + (size_t)(h * 128) * K + (size_t)tt * 64;
    u16* dst = &lds[32768 + (bb * 2 + h) * 8192 + wid * 512];
    gload16(src, dst);
    gload16(src + (size_t)64 * K, dst + 4096);
  };

  f32x4 acc[8][4];
  #pragma unroll
  for (int m = 0; m < 8; ++m)
    #pragma unroll
    for (int n = 0; n < 4; ++n) acc[m][n] = (f32x4){0.f, 0.f, 0.f, 0.f};

  bf16x8 a0[4][2], a1[4][2], b0[2][2], b1[2][2];

  #define READ_A0(B_) { _Pragma("unroll") for (int j = 0; j < 4; ++j) { \
      a0[j][0] = *(const bf16x8*)(aP0 + ((B_)*32768 + j*2048)); \
      a0[j][1] = *(const bf16x8*)(aP1 + ((B_)*32768 + j*2048)); } }
  #define READ_A1(B_) { _Pragma("unroll") for (int j = 0; j < 4; ++j) { \
      a1[j][0] = *(const bf16x8*)(aP0 + ((B_)*32768 + 8192 + j*2048)); \
      a1[j][1] = *(const bf16x8*)(aP1 + ((B_)*32768 + 8192 + j*2048)); } }
  #define READ_B0(B_) { _Pragma("unroll") for (int i = 0; i < 2; ++i) { \
      b0[i][0] = *(const bf16x8*)(bP0 + ((B_)*32768 + i*2048)); \
      b0[i][1] = *(const bf16x8*)(bP1 + ((B_)*32768 + i*2048)); } }
  #define READ_B1(B_) { _Pragma("unroll") for (int i = 0; i < 2; ++i) { \
      b1[i][0] = *(const bf16x8*)(bP0 + ((B_)*32768 + 4096 + i*2048)); \
      b1[i][1] = *(const bf16x8*)(bP1 + ((B_)*32768 + 4096 + i*2048)); } }
  #define MFMA_Q(am, bm, mo, no) { __builtin_amdgcn_s_setprio(1); \
    _Pragma("unroll") for (int j = 0; j < 4; ++j) \
      _Pragma("unroll") for (int i = 0; i < 2; ++i) { \
        acc[(mo) + j][(no) + i] = __builtin_amdgcn_mfma_f32_16x16x32_bf16(am[j][0], bm[i][0], acc[(mo) + j][(no) + i], 0, 0, 0); \
        acc[(mo) + j][(no) + i] = __builtin_amdgcn_mfma_f32_16x16x32_bf16(am[j][1], bm[i][1], acc[(mo) + j][(no) + i], 0, 0, 0); } \
    __builtin_amdgcn_s_setprio(0); }

  const int NK = K >> 6;                                 // 16 or 64 (both even)

  // prologue: 7 half-tiles; vmcnt(6) retires exactly tile 0's 4 halves
  STAGE_B(0, 0, 0); STAGE_B(0, 1, 0); STAGE_A(0, 0, 0); STAGE_A(0, 1, 0);
  STAGE_B(1, 0, 1); STAGE_B(1, 1, 1); STAGE_A(1, 0, 1);
  asm volatile("s_waitcnt vmcnt(6)" ::: "memory");
  BAR();

  // one K-tile, buf index B_ is a compile-time literal (r4 skeleton verbatim)
  #define TILE(B_, t_) { \
    /* P1: reads A-mh0(8)+B-nh0(4); stage A-h1(t+1) */ \
    READ_A0(B_); READ_B0(B_); \
    if ((t_) + 1 < NK) STAGE_A((t_) + 1, 1, (B_) ^ 1); \
    BAR(); LGKM0(); \
    MFMA_Q(a0, b0, 0, 0); \
    BAR(); \
    /* P2: reads B-nh1(4) */ \
    READ_B1(B_); \
    BAR(); LGKM0(); \
    MFMA_Q(a0, b1, 0, 2); \
    BAR(); \
    /* P3: reads A-mh1(8); stage B-h0(t+2) */ \
    READ_A1(B_); \
    if ((t_) + 2 < NK) STAGE_B((t_) + 2, 0, (B_)); \
    BAR(); LGKM0(); \
    MFMA_Q(a1, b1, 4, 2); \
    BAR(); \
    /* P4: no reads; stage B-h1(t+2)+A-h0(t+2); vmcnt once per tile */ \
    if ((t_) + 2 < NK) { STAGE_B((t_) + 2, 1, (B_)); STAGE_A((t_) + 2, 0, (B_)); } \
    BAR(); \
    MFMA_Q(a1, b0, 4, 0); \
    if ((t_) < NK - 2) { asm volatile("s_waitcnt vmcnt(6)" ::: "memory"); } \
    else               { asm volatile("s_waitcnt vmcnt(0)" ::: "memory"); } \
    BAR(); \
    __builtin_amdgcn_sched_barrier(0); }

  for (int t = 0; t < NK; t += 2) {
    TILE(0, t);
    TILE(1, t + 1);
  }
  #undef TILE

  // ---- epilogue: per-wave padded LDS-bounce transpose -> u16x8 stores ----
  __syncthreads();
  float bv[4];
  #pragma unroll
  for (int ni = 0; ni < 4; ++ni) bv[ni] = bias[ct * 256 + wn * 64 + ni * 16 + fr];
  float* ep = (float*)((char*)lds + wid * 4608);         // 16 x 68 floats, padded
  const int row16 = l >> 2, cg = l & 3;
  #pragma unroll
  for (int mi = 0; mi < 8; ++mi) {
    #pragma unroll
    for (int ni = 0; ni < 4; ++ni) {
      f32x4 v = acc[mi][ni];
      #pragma unroll
      for (int j = 0; j < 4; ++j) {
        float f = v[j] + bv[ni];
        if (RELU) f = fmaxf(f, 0.f);
        ep[(fq * 4 + j) * 68 + ni * 16 + fr] = f;        // stride 68: 2-way max
      }
    }
    #pragma unroll
    for (int p = 0; p < 2; ++p) {
      f4 r0 = *(f4*)&ep[row16 * 68 + (cg + p * 4) * 8];
      f4 r1 = *(f4*)&ep[row16 * 68 + (cg + p * 4) * 8 + 4];
      u16x8 o;
      o[0]=f2bf(r0[0]); o[1]=f2bf(r0[1]); o[2]=f2bf(r0[2]); o[3]=f2bf(r0[3]);
      o[4]=f2bf(r1[0]); o[5]=f2bf(r1[1]); o[6]=f2bf(r1[2]); o[7]=f2bf(r1[3]);
      int rr = row0 + wm * 128 + mi * 16 + row16;
      int cc = ct * 256 + wn * 64 + (cg + p * 4) * 8;
      *(u16x8*)&O[(size_t)rr * N + cc] = o;
    }
  }
  #undef READ_A0
  #undef READ_A1
  #undef READ_B0
  #undef READ_B1
  #undef MFMA_Q
}

// ---------------- K9: combine ----------------
__global__ __launch_bounds__(128) void k_combine(
    const u16* __restrict__ eo, const u16* __restrict__ dense_o,
    const float4* __restrict__ tok_wf, const int2* __restrict__ tok_slot,
    float* __restrict__ out)
{
  int t = blockIdx.x;
  int c8 = threadIdx.x;
  float4 wf = tok_wf[t];
  int2 sl = tok_slot[t];
  u16x8 a  = *((const u16x8*)(eo + (size_t)sl.x * D_DIM) + c8);
  u16x8 b  = *((const u16x8*)(eo + (size_t)sl.y * D_DIM) + c8);
  u16x8 dn = *((const u16x8*)(dense_o + (size_t)t * D_DIM) + c8);
  float* op = out + (size_t)t * D_DIM + c8 * 8;
  #pragma unroll
  for (int j = 0; j < 8; ++j) {
    float mo = wf.x * bf2f(a[j]) + wf.y * bf2f(b[j]);
    op[j] = wf.z * mo + wf.w * bf2f(dn[j]);
  }
}

// ---------------- launch ----------------
extern "C" void kernel_launch(void* const* d_in, const int* in_sizes, int n_in,
                              void* d_out, int out_size, void* d_ws, size_t ws_size,
                              hipStream_t stream)
{
  const float* x   = (const float*)d_in[0];
  const float* Wr  = (const float*)d_in[1];
  const float* br  = (const float*)d_in[2];
  const float* Wg  = (const float*)d_in[3];
  const float* bg  = (const float*)d_in[4];
  const float* W1  = (const float*)d_in[5];
  const float* b1  = (const float*)d_in[6];
  const float* W2  = (const float*)d_in[7];
  const float* b2  = (const float*)d_in[8];
  const float* D1  = (const float*)d_in[9];
  const float* d1b = (const float*)d_in[10];
  const float* D2  = (const float*)d_in[11];
  const float* d2b = (const float*)d_in[12];
  float* out = (float*)d_out;

  char* base = (char*)d_ws;
  size_t cur = 0;
  auto alloc = [&](size_t b) -> void* {
    void* p = base + cur; cur = (cur + b + 255) & ~(size_t)255; return p;
  };
  int*    hdr      = (int*)   alloc(256 * sizeof(int));
  int4*   tilemap  = (int4*)  alloc((size_t)RT_MAX * sizeof(int4));
  int4*   tok_sel  = (int4*)  alloc((size_t)T_TOK * sizeof(int4));
  float4* tok_wf   = (float4*)alloc((size_t)T_TOK * sizeof(float4));
  int2*   tok_slot = (int2*)  alloc((size_t)T_TOK * sizeof(int2));
  int*    perm     = (int*)   alloc((size_t)SLOT_MAX * sizeof(int));
  u16*    xb       = (u16*)   alloc((size_t)T_TOK * D_DIM * 2);
  u16*    xg       = (u16*)   alloc((size_t)SLOT_MAX * D_DIM * 2);
  u16*    W1bt     = (u16*)   alloc((size_t)E_NUM * D_DIM * FF_DIM * 2);
  u16*    W2bt     = (u16*)   alloc((size_t)E_NUM * D_DIM * FF_DIM * 2);
  u16*    D1bt     = (u16*)   alloc((size_t)D_DIM * FF_DIM * 2);
  u16*    D2bt     = (u16*)   alloc((size_t)D_DIM * FF_DIM * 2);
  u16*    h_moe    = (u16*)   alloc((size_t)SLOT_MAX * FF_DIM * 2);
  u16*    h_dense  = (u16*)   alloc((size_t)T_TOK * FF_DIM * 2);
  u16*    eo       = (u16*)   alloc((size_t)SLOT_MAX * D_DIM * 2);
  u16*    dense_o  = (u16*)   alloc((size_t)T_TOK * D_DIM * 2);
  (void)in_sizes; (void)n_in; (void)out_size; (void)ws_size; // needs ~475 MB of ws

  k_init     <<<1, 64, 0, stream>>>(hdr);
  k_route    <<<T_TOK / 4, 256, 0, stream>>>(x, Wr, br, Wg, bg, hdr, tok_sel, tok_wf, xb);
  k_offsets  <<<1, 256, 0, stream>>>(hdr, tilemap, perm);
  k_scatter  <<<T_TOK / 256, 256, 0, stream>>>(tok_sel, hdr, perm, tok_slot);
  k_gather   <<<SLOT_MAX / 2, 256, 0, stream>>>(xb, perm, hdr, xg);
  k_tcast_all<<<18 * 1024, 256, 0, stream>>>(W1, W2, D1, D2, W1bt, W2bt, D1bt, D2bt);

  // GEMM1: [slots|tokens] x W1 -> relu -> h   (grid 16x104, K=1024, NK=16)
  k_gemm8p<1><<<dim3(FF_DIM / 256, RT_MAX), 512, 0, stream>>>(
      xg, xb, W1bt, D1bt, b1, d1b, h_moe, h_dense, hdr, tilemap,
      D_DIM, FF_DIM, (long)D_DIM * FF_DIM, FF_DIM, 4);
  // GEMM2: h x W2 -> eo   (grid 4x104, K=4096, NK=64)
  k_gemm8p<0><<<dim3(D_DIM / 256, RT_MAX), 512, 0, stream>>>(
      h_moe, h_dense, W2bt, D2bt, b2, d2b, eo, dense_o, hdr, tilemap,
      FF_DIM, D_DIM, (long)D_DIM * FF_DIM, D_DIM, 2);

  k_combine<<<T_TOK, 128, 0, stream>>>(eo, dense_o, tok_wf, tok_slot, out);
}